// Round 5
// baseline (388.569 us; speedup 1.0000x reference)
//
#include <hip/hip_runtime.h>
#include <hip/hip_bf16.h>
#include <math.h>
#include <stdint.h>

#define T_TOK 8192      // b*l
#define L_SEQ 4096
#define DM    1024
#define DIN   2048
#define DSTATE 128
#define NH    32
#define HD    64
#define CH    64        // chunk length
#define NCH   64        // chunks per batch
#define NBC   128       // B * NCH
#define CONVD 2304
#define NPROJ 2336      // columns of in_proj we actually need (z gate unused)
#define NPAD  2432      // NPROJ padded to multiple of 128
#define PROJ_OFF 2048
#define DPROJ 4384

typedef __bf16 bf16x8 __attribute__((ext_vector_type(8)));
typedef __bf16 bf16x4 __attribute__((ext_vector_type(4)));
typedef float f32x4 __attribute__((ext_vector_type(4)));

__device__ __forceinline__ void gload_lds16(const void* g, void* l) {
  __builtin_amdgcn_global_load_lds(
      (const __attribute__((address_space(1))) void*)(uintptr_t)g,
      (__attribute__((address_space(3))) void*)(uintptr_t)l, 16, 0, 0);
}

// ---------------- K0: fused preprocessing: cast x + transpose both weights --
__global__ __launch_bounds__(256) void k_pre(const float* __restrict__ x,
    __hip_bfloat16* __restrict__ xb, const float* __restrict__ in_w,
    __hip_bfloat16* __restrict__ wib, const float* __restrict__ out_w,
    __hip_bfloat16* __restrict__ wob) {
  __shared__ float s[64][65];
  int bid = blockIdx.x;
  if (bid < 8192) {                       // cast x -> bf16
    int i = (bid * 256 + threadIdx.x) * 4;
    float4 v = *(const float4*)(x + i);
    bf16x4 r;
    r[0] = (__bf16)v.x; r[1] = (__bf16)v.y; r[2] = (__bf16)v.z; r[3] = (__bf16)v.w;
    *(bf16x4*)(xb + i) = r;
    return;
  }
  const float* w; __hip_bfloat16* wt;
  int K, ldsrc, colOff, ncols, kx, ny;
  if (bid < 8800) {                       // in_proj weight transpose
    int b2 = bid - 8192; kx = b2 & 15; ny = b2 >> 4;
    w = in_w; wt = wib; K = DM; ldsrc = DPROJ; colOff = PROJ_OFF; ncols = NPROJ;
  } else {                                // out_proj weight transpose
    int b3 = bid - 8800; kx = b3 & 31; ny = b3 >> 5;
    w = out_w; wt = wob; K = DIN; ldsrc = DM; colOff = 0; ncols = DM;
  }
  int k0 = kx * 64, n0 = ny * 64;
  int c = threadIdx.x & 63, r0 = threadIdx.x >> 6;
  for (int i = 0; i < 16; i++) {
    int r = r0 + 4 * i;
    int ng = n0 + c;
    s[r][c] = (ng < ncols) ? w[(size_t)(k0 + r) * ldsrc + colOff + ng] : 0.f;
  }
  __syncthreads();
  for (int i = 0; i < 16; i++) {
    int a = r0 + 4 * i;
    wt[(size_t)(n0 + a) * K + k0 + c] = __float2bfloat16(s[c][a]);
  }
}

// ---------------- MFMA GEMM v2: 256t x 128n tile, operand-swapped epilogue --
// Each of 4 waves computes 128t x 64n (8 t-frags x 4 n-frags). D[n][t] layout:
// lane holds 4 consecutive n per acc -> vector stores.
template <int KDIM, bool SPLIT>
__global__ __launch_bounds__(256, 2) void k_gemm2(
    const __hip_bfloat16* __restrict__ A, const __hip_bfloat16* __restrict__ Bt,
    float* __restrict__ C, __hip_bfloat16* __restrict__ Cb16,
    float* __restrict__ dtb, const float* __restrict__ dt_bias, int NLD) {
  __shared__ __attribute__((aligned(16))) __hip_bfloat16 sA[256 * 64];  // tokens
  __shared__ __attribute__((aligned(16))) __hip_bfloat16 sB[128 * 64];  // weights
  int tid = threadIdx.x;
  int wid = tid >> 6, lane = tid & 63;
  int t0 = blockIdx.y * 256, n0 = blockIdx.x * 128;
  int wt = (wid >> 1) * 128, wn = (wid & 1) * 64;
  int r15 = lane & 15, quad = lane >> 4;
  int srow = lane >> 3;      // 0..7
  int kcs = lane & 7;        // stored granule

  f32x4 acc[4][8];
  f32x4 zz = {0.f, 0.f, 0.f, 0.f};
#pragma unroll
  for (int mi = 0; mi < 4; mi++)
#pragma unroll
    for (int ti = 0; ti < 8; ti++) acc[mi][ti] = zz;

  const __hip_bfloat16* Abase = A + (size_t)t0 * KDIM;
  const __hip_bfloat16* Bbase = Bt + (size_t)n0 * KDIM;

  for (int k0 = 0; k0 < KDIM; k0 += 64) {
    // stage A: 256 rows, wave stages 64 rows (8 chunks of 8)
#pragma unroll
    for (int c = 0; c < 8; c++) {
      int R0 = wid * 64 + c * 8;
      int row = R0 + srow;
      int kcg = kcs ^ (row & 7);
      gload_lds16(Abase + (size_t)row * KDIM + k0 + kcg * 8, &sA[R0 * 64]);
    }
    // stage B: 128 rows, wave stages 32 rows (4 chunks of 8)
#pragma unroll
    for (int c = 0; c < 4; c++) {
      int R0 = wid * 32 + c * 8;
      int row = R0 + srow;
      int kcg = kcs ^ (row & 7);
      gload_lds16(Bbase + (size_t)row * KDIM + k0 + kcg * 8, &sB[R0 * 64]);
    }
    __syncthreads();
#pragma unroll
    for (int s = 0; s < 2; s++) {
      int sw = ((s << 2) | quad) ^ (r15 & 7);
      bf16x8 wf[4], xf[8];
#pragma unroll
      for (int mi = 0; mi < 4; mi++)
        wf[mi] = *reinterpret_cast<const bf16x8*>(&sB[(wn + mi * 16 + r15) * 64 + sw * 8]);
#pragma unroll
      for (int ti = 0; ti < 8; ti++)
        xf[ti] = *reinterpret_cast<const bf16x8*>(&sA[(wt + ti * 16 + r15) * 64 + sw * 8]);
#pragma unroll
      for (int mi = 0; mi < 4; mi++)
#pragma unroll
        for (int ti = 0; ti < 8; ti++)
          acc[mi][ti] = __builtin_amdgcn_mfma_f32_16x16x32_bf16(wf[mi], xf[ti], acc[mi][ti], 0, 0, 0);
    }
    __syncthreads();
  }

  // epilogue: D[n = quad*4+i within n-frag][t = r15 within t-frag]
#pragma unroll
  for (int ti = 0; ti < 8; ti++) {
    int t = t0 + wt + ti * 16 + r15;
#pragma unroll
    for (int mi = 0; mi < 4; mi++) {
      int n = n0 + wn + mi * 16 + quad * 4;
      f32x4 v = acc[mi][ti];
      if (SPLIT) {
        if (n < CONVD) {
          bf16x4 r;
#pragma unroll
          for (int i = 0; i < 4; i++) r[i] = (__bf16)v[i];
          *(bf16x4*)(Cb16 + (size_t)t * CONVD + n) = r;
        } else {
#pragma unroll
          for (int i = 0; i < 4; i++) {
            int ni = n + i;
            if (ni < NPROJ) {
              int h = ni - CONVD;
              float z = v[i] + dt_bias[h];
              float sp = (z > 20.f) ? z : log1pf(__expf(z));
              dtb[t * NH + h] = sp;
            }
          }
        }
      } else {
        *(float4*)(C + (size_t)t * NLD + n) = *(float4*)&v;
      }
    }
  }
}

// ---------------- K2: depthwise causal conv(4) + bias + SiLU (4 ch/thread) --
__global__ __launch_bounds__(256) void k_conv(const __hip_bfloat16* __restrict__ xbc,
    const float* __restrict__ cw, const float* __restrict__ cb,
    __hip_bfloat16* __restrict__ xh, __hip_bfloat16* __restrict__ Bm,
    __hip_bfloat16* __restrict__ Cm) {
  int pi = blockIdx.x * 256 + threadIdx.x;
  if (pi >= CONVD / 4) return;
  int ch = pi * 4;
  int t = blockIdx.y;
  int l = t & (L_SEQ - 1);
  float4 cb4 = *(const float4*)(cb + ch);
  float acc[4] = {cb4.x, cb4.y, cb4.z, cb4.w};
#pragma unroll
  for (int j = 0; j < 4; j++) {
    int ls = l - 3 + j;
    if (ls >= 0) {
      bf16x4 v = *(const bf16x4*)(xbc + (size_t)(t - 3 + j) * CONVD + ch);
      float4 w4 = *(const float4*)(cw + j * CONVD + ch);
      acc[0] += (float)v[0] * w4.x;
      acc[1] += (float)v[1] * w4.y;
      acc[2] += (float)v[2] * w4.z;
      acc[3] += (float)v[3] * w4.w;
    }
  }
  bf16x4 r;
#pragma unroll
  for (int i = 0; i < 4; i++) {
    float sv = acc[i] / (1.f + __expf(-acc[i]));
    r[i] = (__bf16)sv;
  }
  if (ch < DIN)                 *(bf16x4*)(xh + (size_t)t * DIN + ch) = r;
  else if (ch < DIN + DSTATE)   *(bf16x4*)(Bm + (size_t)t * DSTATE + ch - DIN) = r;
  else                          *(bf16x4*)(Cm + (size_t)t * DSTATE + ch - DIN - DSTATE) = r;
}

// ---------------- K3: per-(b,c,h) inclusive cumsum of A*dt + chunk decay ----
__global__ void k_acum(const float* __restrict__ dtb, const float* __restrict__ A_log,
                       float* __restrict__ acum, float* __restrict__ echunk) {
  int h = threadIdx.x;     // 32
  int bc = blockIdx.x;     // 0..127
  int base = bc * CH;
  float a = -__expf(A_log[h]);
  float s = 0.f;
  for (int l = 0; l < CH; l++) {
    s += a * dtb[(base + l) * NH + h];
    acum[(base + l) * NH + h] = s;
  }
  echunk[bc * NH + h] = __expf(s);
}

// ---------------- K4: fused SSD per (chunk, 8 heads): G once -> per-head ----
// All transposed LDS arrays use stride-64 XOR-granule layout: element (row, k)
// stored at row*64 + ((k>>3)^(row&7))*8 + (k&7). Store/read swizzles cancel.
__global__ __launch_bounds__(256) void k_ssd1(
    const __hip_bfloat16* __restrict__ xh, const __hip_bfloat16* __restrict__ Bm,
    const __hip_bfloat16* __restrict__ Cm, const float* __restrict__ dtb,
    const float* __restrict__ acum, const float* __restrict__ Dp,
    __hip_bfloat16* __restrict__ ypart, __hip_bfloat16* __restrict__ statesT) {
  __shared__ __attribute__((aligned(16))) char smem[32768 + 8192 + 6144];
  __hip_bfloat16* Cb  = (__hip_bfloat16*)smem;            // 64x128 swz (phase 1)
  __hip_bfloat16* Bb  = Cb + 64 * 128;                    // 64x128 swz (phase 1)
  __hip_bfloat16* BT  = (__hip_bfloat16*)smem;            // 128x64 [n][l] (phase 2, alias)
  __hip_bfloat16* xdT = BT + 128 * 64;                    // 64x64 [p][l] x*dt
  __hip_bfloat16* xsT = xdT + 64 * 64;                    // 64x64 [p][l] x*dt*dec
  __hip_bfloat16* P   = (__hip_bfloat16*)(smem + 32768);  // 64x64 [l][s]
  float* acvA = (float*)(smem + 32768 + 8192);            // [8][64]
  float* dtsA = acvA + 512;
  float* decA = dtsA + 512;

  int bc = blockIdx.x, h0 = blockIdx.y * 8;
  int base = bc * CH;
  int tid = threadIdx.x, wid = tid >> 6, lane = tid & 63;
  int r15 = lane & 15, quad = lane >> 4;
  int wm = wid * 16;
  f32x4 zz = {0.f, 0.f, 0.f, 0.f};

  // preload per-head scalars (8 heads x 64 positions)
  for (int i = 0; i < 2; i++) {
    int idx = tid + 256 * i;
    int hh = idx >> 6, l = idx & 63;
    int h = h0 + hh;
    float a = acum[(base + l) * NH + h];
    float alast = acum[(base + 63) * NH + h];
    acvA[hh * 64 + l] = a;
    dtsA[hh * 64 + l] = dtb[(base + l) * NH + h];
    decA[hh * 64 + l] = __expf(alast - a);
  }
  // stage Cb/Bb via async gload (row-granule XOR swizzle on global side)
  {
    int srow = lane >> 4, g = lane & 15;
    for (int c = 0; c < 4; c++) {
      int R0 = wid * 16 + c * 4;
      int r = R0 + srow;
      int gs = g ^ (r & 7);
      gload_lds16(Cm + (size_t)(base + r) * DSTATE + gs * 8, &Cb[R0 * DSTATE]);
      gload_lds16(Bm + (size_t)(base + r) * DSTATE + gs * 8, &Bb[R0 * DSTATE]);
    }
  }
  __syncthreads();

  // --- G = C.B^T once: wave strip rows wm..wm+15 x all 64 s (K=128)
  f32x4 accg[4];
  for (int ct = 0; ct < 4; ct++) accg[ct] = zz;
#pragma unroll
  for (int ks = 0; ks < 4; ks++) {
    int arow = wm + r15;
    bf16x8 af = *(const bf16x8*)&Cb[arow * 128 + (((ks * 4 + quad) ^ (r15 & 7)) << 3)];
#pragma unroll
    for (int ct = 0; ct < 4; ct++) {
      int brow = ct * 16 + r15;
      bf16x8 bfr = *(const bf16x8*)&Bb[brow * 128 + (((ks * 4 + quad) ^ (r15 & 7)) << 3)];
      accg[ct] = __builtin_amdgcn_mfma_f32_16x16x32_bf16(af, bfr, accg[ct], 0, 0, 0);
    }
  }
  __syncthreads();   // Cb/Bb dead; region reused below

  int l0 = (tid & 15) * 4;     // 4 consecutive l (same granule: l0%8 in {0,4})
  int q0 = tid >> 4;           // 0..15
  int go = l0 & 7;             // offset within granule
  int gl = l0 >> 3;            // true granule of l0

  for (int hh = 0; hh < 8; hh++) {
    int h = h0 + hh;
    if (hh == 0) {
      // build BT[n][l] once (head-independent, decay folded into xs)
      int n0 = q0 * 8;
      __bf16 tmp[8][4];
#pragma unroll
      for (int dl = 0; dl < 4; dl++) {
        bf16x8 bv = *(const bf16x8*)(Bm + (size_t)(base + l0 + dl) * DSTATE + n0);
#pragma unroll
        for (int dn = 0; dn < 8; dn++) tmp[dn][dl] = bv[dn];
      }
#pragma unroll
      for (int dn = 0; dn < 8; dn++) {
        int n = n0 + dn;
        bf16x4 pk = {tmp[dn][0], tmp[dn][1], tmp[dn][2], tmp[dn][3]};
        *(bf16x4*)&BT[n * 64 + ((gl ^ (n & 7)) << 3) + go] = pk;
      }
    }
    // build xdT (x*dt) and xsT (x*dt*dec) for this head: 4l x 4p per thread
    {
      int p0 = q0 * 4;
      __bf16 td[4][4], ts[4][4];
#pragma unroll
      for (int dl = 0; dl < 4; dl++) {
        int l = l0 + dl;
        bf16x4 xv = *(const bf16x4*)(xh + (size_t)(base + l) * DIN + h * HD + p0);
        float dt = dtsA[hh * 64 + l];
        float ds = dt * decA[hh * 64 + l];
#pragma unroll
        for (int dp = 0; dp < 4; dp++) {
          float xf = (float)xv[dp];
          td[dp][dl] = (__bf16)(xf * dt);
          ts[dp][dl] = (__bf16)(xf * ds);
        }
      }
#pragma unroll
      for (int dp = 0; dp < 4; dp++) {
        int p = p0 + dp;
        int off = p * 64 + ((gl ^ (p & 7)) << 3) + go;
        bf16x4 pd = {td[dp][0], td[dp][1], td[dp][2], td[dp][3]};
        bf16x4 ps = {ts[dp][0], ts[dp][1], ts[dp][2], ts[dp][3]};
        *(bf16x4*)&xdT[off] = pd;
        *(bf16x4*)&xsT[off] = ps;
      }
    }
    __syncthreads();

    // --- P = mask(G * decay) -> LDS (wave-private rows wm..wm+15)
#pragma unroll
    for (int ct = 0; ct < 4; ct++) {
      int s = ct * 16 + r15;
      float as = acvA[hh * 64 + s];
#pragma unroll
      for (int i = 0; i < 4; i++) {
        int l = wm + quad * 4 + i;
        float pv = (s <= l) ? accg[ct][i] * __expf(acvA[hh * 64 + l] - as) : 0.f;
        P[l * 64 + (((s >> 3) ^ (l & 7)) << 3) + (s & 7)] = __float2bfloat16(pv);
      }
    }
    // --- Y_diag = P.xd (K=64) + xh*D
    f32x4 accy[4];
    for (int ct = 0; ct < 4; ct++) accy[ct] = zz;
#pragma unroll
    for (int ks = 0; ks < 2; ks++) {
      int arow = wm + r15;
      bf16x8 af = *(const bf16x8*)&P[arow * 64 + (((ks * 4 + quad) ^ (r15 & 7)) << 3)];
#pragma unroll
      for (int ct = 0; ct < 4; ct++) {
        int brow = ct * 16 + r15;
        bf16x8 bfr = *(const bf16x8*)&xdT[brow * 64 + (((ks * 4 + quad) ^ (r15 & 7)) << 3)];
        accy[ct] = __builtin_amdgcn_mfma_f32_16x16x32_bf16(af, bfr, accy[ct], 0, 0, 0);
      }
    }
    float Dh = Dp[h];
#pragma unroll
    for (int ct = 0; ct < 4; ct++) {
      int p = ct * 16 + r15;
#pragma unroll
      for (int i = 0; i < 4; i++) {
        int l = wm + quad * 4 + i;
        float xv = __bfloat162float(xh[(size_t)(base + l) * DIN + h * HD + p]);
        ypart[(size_t)(base + l) * DIN + h * HD + p] = __float2bfloat16(accy[ct][i] + xv * Dh);
      }
    }
    // --- S^T[p][n] = sum_l xs[l][p] * B[l][n]  (K=64, wave strip over p)
    f32x4 accs[8];
    for (int ct = 0; ct < 8; ct++) accs[ct] = zz;
#pragma unroll
    for (int ks = 0; ks < 2; ks++) {
      int arow = wm + r15;   // p row
      bf16x8 af = *(const bf16x8*)&xsT[arow * 64 + (((ks * 4 + quad) ^ (r15 & 7)) << 3)];
#pragma unroll
      for (int ct = 0; ct < 8; ct++) {
        int brow = ct * 16 + r15;   // n row
        bf16x8 bfr = *(const bf16x8*)&BT[brow * 64 + (((ks * 4 + quad) ^ (r15 & 7)) << 3)];
        accs[ct] = __builtin_amdgcn_mfma_f32_16x16x32_bf16(af, bfr, accs[ct], 0, 0, 0);
      }
    }
    size_t sbase = ((size_t)bc * NH + h) * (HD * DSTATE);
#pragma unroll
    for (int ct = 0; ct < 8; ct++) {
      int n = ct * 16 + r15;
#pragma unroll
      for (int i = 0; i < 4; i++) {
        int p = wm + quad * 4 + i;
        statesT[sbase + (size_t)p * DSTATE + n] = __float2bfloat16(accs[ct][i]);
      }
    }
    __syncthreads();   // before next head overwrites xdT/xsT
  }
}

// ---------------- K5: inter-chunk scan (in-place, layout [bc][h][p][n]) ----
__global__ __launch_bounds__(256) void k_scan(__hip_bfloat16* __restrict__ states,
    const float* __restrict__ echunk) {
  int idx = blockIdx.x * 256 + threadIdx.x;   // 524288
  int inner = idx & 8191;          // p*128+n
  int h = (idx >> 13) & 31;
  int b = idx >> 18;
  float run = 0.f;
  for (int c = 0; c < NCH; c++) {
    int bc = b * NCH + c;
    size_t off = ((size_t)bc * NH + h) * 8192 + inner;
    float tmp = __bfloat162float(states[off]);
    states[off] = __float2bfloat16(run);
    run = run * echunk[bc * NH + h] + tmp;
  }
}

// ---------------- K6: y += exp(acum) * (C . S_in^T), in-place bf16 ---------
__global__ __launch_bounds__(256) void k_ssd2(
    const __hip_bfloat16* __restrict__ statesT, const __hip_bfloat16* __restrict__ Cm,
    const float* __restrict__ acum, __hip_bfloat16* __restrict__ y) {
  __shared__ __attribute__((aligned(16))) __hip_bfloat16 Cb[64 * 128];  // [l][n] swz
  __shared__ __attribute__((aligned(16))) __hip_bfloat16 Sb[64 * 128];  // [p][n] swz
  __shared__ __attribute__((aligned(16))) __hip_bfloat16 Yt[64 * 64];   // [l][p]
  __shared__ float aout[64];
  int bc = blockIdx.x, h = blockIdx.y;
  int base = bc * CH;
  int tid = threadIdx.x, wid = tid >> 6, lane = tid & 63;
  int r15 = lane & 15, quad = lane >> 4;
  int wm = wid * 16;

  if (tid < 64) aout[tid] = __expf(acum[(base + tid) * NH + h]);
  size_t sbase = ((size_t)bc * NH + h) * (HD * DSTATE);
  {
    int srow = lane >> 4, g = lane & 15;
    for (int c = 0; c < 4; c++) {
      int R0 = wid * 16 + c * 4;
      int r = R0 + srow;
      int gs = g ^ (r & 7);
      gload_lds16(Cm + (size_t)(base + r) * DSTATE + gs * 8, &Cb[R0 * DSTATE]);
      gload_lds16(statesT + sbase + (size_t)r * DSTATE + gs * 8, &Sb[R0 * DSTATE]);
    }
    for (int c = 0; c < 2; c++) {
      int R0 = wid * 16 + c * 8;
      int r = R0 + (lane >> 3);
      gload_lds16(y + (size_t)(base + r) * DIN + h * HD + (lane & 7) * 8, &Yt[R0 * 64]);
    }
  }
  __syncthreads();

  f32x4 acc[4];
  f32x4 zz = {0.f, 0.f, 0.f, 0.f};
  for (int ct = 0; ct < 4; ct++) acc[ct] = zz;
#pragma unroll
  for (int ks = 0; ks < 4; ks++) {
    int arow = wm + r15;
    bf16x8 af = *(const bf16x8*)&Cb[arow * 128 + (((ks * 4 + quad) ^ (r15 & 7)) << 3)];
#pragma unroll
    for (int ct = 0; ct < 4; ct++) {
      int brow = ct * 16 + r15;
      bf16x8 bfr = *(const bf16x8*)&Sb[brow * 128 + (((ks * 4 + quad) ^ (r15 & 7)) << 3)];
      acc[ct] = __builtin_amdgcn_mfma_f32_16x16x32_bf16(af, bfr, acc[ct], 0, 0, 0);
    }
  }
#pragma unroll
  for (int ct = 0; ct < 4; ct++) {
    int p = ct * 16 + r15;
#pragma unroll
    for (int i = 0; i < 4; i++) {
      int l = wm + quad * 4 + i;
      float v = __bfloat162float(Yt[l * 64 + p]) + aout[l] * acc[ct][i];
      y[(size_t)(base + l) * DIN + h * HD + p] = __float2bfloat16(v);
    }
  }
}

extern "C" void kernel_launch(void* const* d_in, const int* in_sizes, int n_in,
                              void* d_out, int out_size, void* d_ws, size_t ws_size,
                              hipStream_t stream) {
  const float* x       = (const float*)d_in[0];
  const float* in_w    = (const float*)d_in[1];
  const float* conv_w  = (const float*)d_in[2];
  const float* conv_b  = (const float*)d_in[3];
  const float* dt_bias = (const float*)d_in[4];
  const float* A_log   = (const float*)d_in[5];
  const float* Dp      = (const float*)d_in[6];
  const float* out_w   = (const float*)d_in[7];
  float* out = (float*)d_out;

  char* cur = (char*)d_ws;
  auto alloc = [&](size_t bytes) {
    char* p = cur;
    cur += (bytes + 255) & ~(size_t)255;
    return p;
  };
  __hip_bfloat16* xbc   = (__hip_bfloat16*)alloc((size_t)T_TOK * CONVD * 2);
  float* dtb            = (float*)alloc((size_t)T_TOK * NH * 4);
  float* acum           = (float*)alloc((size_t)T_TOK * NH * 4);
  float* echunk         = (float*)alloc((size_t)NBC * NH * 4);
  __hip_bfloat16* xh    = (__hip_bfloat16*)alloc((size_t)T_TOK * DIN * 2);
  __hip_bfloat16* Bm    = (__hip_bfloat16*)alloc((size_t)T_TOK * DSTATE * 2);
  __hip_bfloat16* Cm    = (__hip_bfloat16*)alloc((size_t)T_TOK * DSTATE * 2);
  __hip_bfloat16* ybuf  = (__hip_bfloat16*)alloc((size_t)T_TOK * DIN * 2);
  __hip_bfloat16* states= (__hip_bfloat16*)alloc((size_t)NBC * NH * HD * DSTATE * 2);
  __hip_bfloat16* wib   = (__hip_bfloat16*)alloc((size_t)NPAD * DM * 2);
  __hip_bfloat16* wob   = (__hip_bfloat16*)alloc((size_t)DIN * DM * 2);
  __hip_bfloat16* xb    = states;   // alias: xb dead before k_ssd1 writes states

  k_pre    <<<dim3(9312), 256, 0, stream>>>(x, xb, in_w, wib, out_w, wob);
  k_gemm2<DM, true><<<dim3(NPAD / 128, T_TOK / 256), 256, 0, stream>>>(
      xb, wib, nullptr, xbc, dtb, dt_bias, 0);
  k_conv   <<<dim3(3, T_TOK), 256, 0, stream>>>(xbc, conv_w, conv_b, xh, Bm, Cm);
  k_acum   <<<dim3(NBC),       32, 0, stream>>>(dtb, A_log, acum, echunk);
  k_ssd1   <<<dim3(NBC, 4),   256, 0, stream>>>(xh, Bm, Cm, dtb, acum, Dp, ybuf, states);
  k_scan   <<<dim3(2048),     256, 0, stream>>>(states, echunk);
  k_ssd2   <<<dim3(NBC, NH),  256, 0, stream>>>(states, Cm, acum, ybuf);
  k_gemm2<DIN, false><<<dim3(DM / 128, T_TOK / 256), 256, 0, stream>>>(
      ybuf, wob, out, nullptr, nullptr, nullptr, DM);
}

// Round 6
// 355.978 us; speedup vs baseline: 1.0916x; 1.0916x over previous
//
#include <hip/hip_runtime.h>
#include <hip/hip_bf16.h>
#include <math.h>
#include <stdint.h>

#define T_TOK 8192      // b*l
#define L_SEQ 4096
#define DM    1024
#define DIN   2048
#define DSTATE 128
#define NH    32
#define HD    64
#define CH    64        // chunk length
#define NCH   64        // chunks per batch
#define NBC   128       // B * NCH
#define CONVD 2304
#define NPROJ 2336      // columns of in_proj we actually need (z gate unused)
#define NPAD  2432      // NPROJ padded to multiple of 128
#define PROJ_OFF 2048
#define DPROJ 4384

typedef __bf16 bf16x8 __attribute__((ext_vector_type(8)));
typedef __bf16 bf16x4 __attribute__((ext_vector_type(4)));
typedef float f32x4 __attribute__((ext_vector_type(4)));

__device__ __forceinline__ void gload_lds16(const void* g, void* l) {
  __builtin_amdgcn_global_load_lds(
      (const __attribute__((address_space(1))) void*)(uintptr_t)g,
      (__attribute__((address_space(3))) void*)(uintptr_t)l, 16, 0, 0);
}

// ---------------- K0: fused preprocessing: cast x + transpose both weights --
__global__ __launch_bounds__(256) void k_pre(const float* __restrict__ x,
    __hip_bfloat16* __restrict__ xb, const float* __restrict__ in_w,
    __hip_bfloat16* __restrict__ wib, const float* __restrict__ out_w,
    __hip_bfloat16* __restrict__ wob) {
  __shared__ float s[64][65];
  int bid = blockIdx.x;
  if (bid < 8192) {                       // cast x -> bf16
    int i = (bid * 256 + threadIdx.x) * 4;
    float4 v = *(const float4*)(x + i);
    bf16x4 r;
    r[0] = (__bf16)v.x; r[1] = (__bf16)v.y; r[2] = (__bf16)v.z; r[3] = (__bf16)v.w;
    *(bf16x4*)(xb + i) = r;
    return;
  }
  const float* w; __hip_bfloat16* wt;
  int K, ldsrc, colOff, ncols, kx, ny;
  if (bid < 8800) {                       // in_proj weight transpose
    int b2 = bid - 8192; kx = b2 & 15; ny = b2 >> 4;
    w = in_w; wt = wib; K = DM; ldsrc = DPROJ; colOff = PROJ_OFF; ncols = NPROJ;
  } else {                                // out_proj weight transpose
    int b3 = bid - 8800; kx = b3 & 31; ny = b3 >> 5;
    w = out_w; wt = wob; K = DIN; ldsrc = DM; colOff = 0; ncols = DM;
  }
  int k0 = kx * 64, n0 = ny * 64;
  int c = threadIdx.x & 63, r0 = threadIdx.x >> 6;
  for (int i = 0; i < 16; i++) {
    int r = r0 + 4 * i;
    int ng = n0 + c;
    s[r][c] = (ng < ncols) ? w[(size_t)(k0 + r) * ldsrc + colOff + ng] : 0.f;
  }
  __syncthreads();
  for (int i = 0; i < 16; i++) {
    int a = r0 + 4 * i;
    wt[(size_t)(n0 + a) * K + k0 + c] = __float2bfloat16(s[c][a]);
  }
}

// ---------------- MFMA GEMM v3: 128x128 tile, operand-swapped epilogue ------
// 4 waves, each 64t x 64n via 4x4 mfma. mfma(wf, xf): D reg-dim = n (4 consec
// per lane) -> vector stores.
template <int KDIM, bool SPLIT>
__global__ __launch_bounds__(256) void k_gemm3(
    const __hip_bfloat16* __restrict__ A, const __hip_bfloat16* __restrict__ Bt,
    float* __restrict__ C, __hip_bfloat16* __restrict__ Cb16,
    float* __restrict__ dtb, const float* __restrict__ dt_bias, int NLD) {
  __shared__ __attribute__((aligned(16))) __hip_bfloat16 sA[128 * 64];
  __shared__ __attribute__((aligned(16))) __hip_bfloat16 sB[128 * 64];
  int tid = threadIdx.x;
  int wid = tid >> 6, lane = tid & 63;
  int t0 = blockIdx.y * 128, n0 = blockIdx.x * 128;
  int wm = (wid >> 1) * 64, wn = (wid & 1) * 64;
  int r15 = lane & 15, quad = lane >> 4;
  int srow = lane >> 3;
  int kcs = lane & 7;

  f32x4 acc[4][4];
  f32x4 zz = {0.f, 0.f, 0.f, 0.f};
  for (int ni = 0; ni < 4; ni++)
    for (int ti = 0; ti < 4; ti++) acc[ni][ti] = zz;

  const __hip_bfloat16* Abase = A + (size_t)t0 * KDIM;
  const __hip_bfloat16* Bbase = Bt + (size_t)n0 * KDIM;

  for (int k0 = 0; k0 < KDIM; k0 += 64) {
    for (int c = 0; c < 4; c++) {
      int R0 = (wid * 4 + c) * 8;
      int row = R0 + srow;
      int kcg = kcs ^ (row & 7);
      gload_lds16(Abase + (size_t)row * KDIM + k0 + kcg * 8, &sA[R0 * 64]);
      gload_lds16(Bbase + (size_t)row * KDIM + k0 + kcg * 8, &sB[R0 * 64]);
    }
    __syncthreads();
#pragma unroll
    for (int s = 0; s < 2; s++) {
      int sw = ((s << 2) | quad) ^ (r15 & 7);
      bf16x8 wf[4], xf[4];
#pragma unroll
      for (int ni = 0; ni < 4; ni++)
        wf[ni] = *reinterpret_cast<const bf16x8*>(&sB[(wn + ni * 16 + r15) * 64 + sw * 8]);
#pragma unroll
      for (int ti = 0; ti < 4; ti++)
        xf[ti] = *reinterpret_cast<const bf16x8*>(&sA[(wm + ti * 16 + r15) * 64 + sw * 8]);
#pragma unroll
      for (int ni = 0; ni < 4; ni++)
#pragma unroll
        for (int ti = 0; ti < 4; ti++)
          acc[ni][ti] = __builtin_amdgcn_mfma_f32_16x16x32_bf16(wf[ni], xf[ti], acc[ni][ti], 0, 0, 0);
    }
    __syncthreads();
  }

  // epilogue: D[n = quad*4+i][t = r15], vector stores over n
#pragma unroll
  for (int ni = 0; ni < 4; ni++) {
    int n = n0 + wn + ni * 16 + quad * 4;
#pragma unroll
    for (int ti = 0; ti < 4; ti++) {
      int t = t0 + wm + ti * 16 + r15;
      f32x4 v = acc[ni][ti];
      if (SPLIT) {
        if (n < CONVD) {
          bf16x4 r;
#pragma unroll
          for (int i = 0; i < 4; i++) r[i] = (__bf16)v[i];
          *(bf16x4*)(Cb16 + (size_t)t * CONVD + n) = r;
        } else if (n < NPROJ) {     // [CONVD, NPROJ) — 4-aligned boundary
#pragma unroll
          for (int i = 0; i < 4; i++) {
            int h = n + i - CONVD;
            float z = v[i] + dt_bias[h];
            float sp = (z > 20.f) ? z : log1pf(__expf(z));
            dtb[t * NH + h] = sp;
          }
        }
      } else {
        *(float4*)(C + (size_t)t * NLD + n) = *(float4*)&v;
      }
    }
  }
}

// ---------------- K2: depthwise causal conv(4) + bias + SiLU (4 ch/thread) --
__global__ __launch_bounds__(256) void k_conv(const __hip_bfloat16* __restrict__ xbc,
    const float* __restrict__ cw, const float* __restrict__ cb,
    __hip_bfloat16* __restrict__ xh, __hip_bfloat16* __restrict__ Bm,
    __hip_bfloat16* __restrict__ Cm) {
  int pi = blockIdx.x * 256 + threadIdx.x;
  if (pi >= CONVD / 4) return;
  int ch = pi * 4;
  int t = blockIdx.y;
  int l = t & (L_SEQ - 1);
  float4 cb4 = *(const float4*)(cb + ch);
  float acc[4] = {cb4.x, cb4.y, cb4.z, cb4.w};
#pragma unroll
  for (int j = 0; j < 4; j++) {
    int ls = l - 3 + j;
    if (ls >= 0) {
      bf16x4 v = *(const bf16x4*)(xbc + (size_t)(t - 3 + j) * CONVD + ch);
      float4 w4 = *(const float4*)(cw + j * CONVD + ch);
      acc[0] += (float)v[0] * w4.x;
      acc[1] += (float)v[1] * w4.y;
      acc[2] += (float)v[2] * w4.z;
      acc[3] += (float)v[3] * w4.w;
    }
  }
  bf16x4 r;
#pragma unroll
  for (int i = 0; i < 4; i++) {
    float sv = acc[i] / (1.f + __expf(-acc[i]));
    r[i] = (__bf16)sv;
  }
  if (ch < DIN)                 *(bf16x4*)(xh + (size_t)t * DIN + ch) = r;
  else if (ch < DIN + DSTATE)   *(bf16x4*)(Bm + (size_t)t * DSTATE + ch - DIN) = r;
  else                          *(bf16x4*)(Cm + (size_t)t * DSTATE + ch - DIN - DSTATE) = r;
}

// ---------------- K4: fused SSD per (chunk, 8 heads), acum folded in --------
// All transposed LDS arrays use stride-64 XOR-granule layout: element (row, k)
// stored at row*64 + ((k>>3)^(row&7))*8 + (k&7). Store/read swizzles cancel.
__global__ __launch_bounds__(256) void k_ssd1(
    const __hip_bfloat16* __restrict__ xh, const __hip_bfloat16* __restrict__ Bm,
    const __hip_bfloat16* __restrict__ Cm, const float* __restrict__ dtb,
    const float* __restrict__ A_log, const float* __restrict__ Dp,
    __hip_bfloat16* __restrict__ ypart, __hip_bfloat16* __restrict__ statesT,
    float* __restrict__ acum_out, float* __restrict__ echunk) {
  __shared__ __attribute__((aligned(16))) char smem[32768 + 8192 + 6144];
  __hip_bfloat16* Cb  = (__hip_bfloat16*)smem;            // 64x128 swz (phase 1)
  __hip_bfloat16* Bb  = Cb + 64 * 128;                    // 64x128 swz (phase 1)
  __hip_bfloat16* BT  = (__hip_bfloat16*)smem;            // 128x64 [n][l] (phase 2, alias)
  __hip_bfloat16* xdT = BT + 128 * 64;                    // 64x64 [p][l] x*dt
  __hip_bfloat16* xsT = xdT + 64 * 64;                    // 64x64 [p][l] x*dt*dec
  __hip_bfloat16* P   = (__hip_bfloat16*)(smem + 32768);  // 64x64 [l][s]
  float* acvA = (float*)(smem + 32768 + 8192);            // [8][64]
  float* dtsA = acvA + 512;
  float* decA = dtsA + 512;

  int bc = blockIdx.x, h0 = blockIdx.y * 8;
  int base = bc * CH;
  int tid = threadIdx.x, wid = tid >> 6, lane = tid & 63;
  int r15 = lane & 15, quad = lane >> 4;
  int wm = wid * 16;
  f32x4 zz = {0.f, 0.f, 0.f, 0.f};

  // stage Cb/Bb via async gload (row-granule XOR swizzle on global side)
  {
    int srow = lane >> 4, g = lane & 15;
    for (int c = 0; c < 4; c++) {
      int R0 = wid * 16 + c * 4;
      int r = R0 + srow;
      int gs = g ^ (r & 7);
      gload_lds16(Cm + (size_t)(base + r) * DSTATE + gs * 8, &Cb[R0 * DSTATE]);
      gload_lds16(Bm + (size_t)(base + r) * DSTATE + gs * 8, &Bb[R0 * DSTATE]);
    }
  }
  // preload dt (8 heads x 64 positions)
  for (int i = 0; i < 2; i++) {
    int idx = tid + 256 * i;
    int hh = idx >> 6, l = idx & 63;
    dtsA[hh * 64 + l] = dtb[(base + l) * NH + h0 + hh];
  }
  __syncthreads();
  // in-block cumsum of A*dt (one serial lane per head; 64 fp32 adds)
  if (tid < 8) {
    int h = h0 + tid;
    float a = -__expf(A_log[h]);
    float s = 0.f;
    for (int l = 0; l < CH; l++) {
      s += a * dtsA[tid * 64 + l];
      acvA[tid * 64 + l] = s;
    }
    echunk[bc * NH + h] = __expf(s);
  }
  __syncthreads();
  // dec + persist acum for k_ssd2
  for (int i = 0; i < 2; i++) {
    int idx = tid + 256 * i;
    int hh = idx >> 6, l = idx & 63;
    float a = acvA[hh * 64 + l];
    decA[hh * 64 + l] = __expf(acvA[hh * 64 + 63] - a);
    acum_out[(base + l) * NH + h0 + hh] = a;
  }

  // --- G = C.B^T once: wave strip rows wm..wm+15 x all 64 s (K=128)
  f32x4 accg[4];
  for (int ct = 0; ct < 4; ct++) accg[ct] = zz;
#pragma unroll
  for (int ks = 0; ks < 4; ks++) {
    int arow = wm + r15;
    bf16x8 af = *(const bf16x8*)&Cb[arow * 128 + (((ks * 4 + quad) ^ (r15 & 7)) << 3)];
#pragma unroll
    for (int ct = 0; ct < 4; ct++) {
      int brow = ct * 16 + r15;
      bf16x8 bfr = *(const bf16x8*)&Bb[brow * 128 + (((ks * 4 + quad) ^ (r15 & 7)) << 3)];
      accg[ct] = __builtin_amdgcn_mfma_f32_16x16x32_bf16(af, bfr, accg[ct], 0, 0, 0);
    }
  }
  __syncthreads();   // Cb/Bb dead; region reused below

  int l0 = (tid & 15) * 4;     // 4 consecutive l (same granule: l0%8 in {0,4})
  int q0 = tid >> 4;           // 0..15
  int go = l0 & 7;             // offset within granule
  int gl = l0 >> 3;            // true granule of l0

  for (int hh = 0; hh < 8; hh++) {
    int h = h0 + hh;
    if (hh == 0) {
      // build BT[n][l] once (head-independent, decay folded into xs)
      int n0 = q0 * 8;
      __bf16 tmp[8][4];
#pragma unroll
      for (int dl = 0; dl < 4; dl++) {
        bf16x8 bv = *(const bf16x8*)(Bm + (size_t)(base + l0 + dl) * DSTATE + n0);
#pragma unroll
        for (int dn = 0; dn < 8; dn++) tmp[dn][dl] = bv[dn];
      }
#pragma unroll
      for (int dn = 0; dn < 8; dn++) {
        int n = n0 + dn;
        bf16x4 pk = {tmp[dn][0], tmp[dn][1], tmp[dn][2], tmp[dn][3]};
        *(bf16x4*)&BT[n * 64 + ((gl ^ (n & 7)) << 3) + go] = pk;
      }
    }
    // build xdT (x*dt) and xsT (x*dt*dec) for this head: 4l x 4p per thread
    {
      int p0 = q0 * 4;
      __bf16 td[4][4], ts[4][4];
#pragma unroll
      for (int dl = 0; dl < 4; dl++) {
        int l = l0 + dl;
        bf16x4 xv = *(const bf16x4*)(xh + (size_t)(base + l) * DIN + h * HD + p0);
        float dt = dtsA[hh * 64 + l];
        float ds = dt * decA[hh * 64 + l];
#pragma unroll
        for (int dp = 0; dp < 4; dp++) {
          float xf = (float)xv[dp];
          td[dp][dl] = (__bf16)(xf * dt);
          ts[dp][dl] = (__bf16)(xf * ds);
        }
      }
#pragma unroll
      for (int dp = 0; dp < 4; dp++) {
        int p = p0 + dp;
        int off = p * 64 + ((gl ^ (p & 7)) << 3) + go;
        bf16x4 pd = {td[dp][0], td[dp][1], td[dp][2], td[dp][3]};
        bf16x4 ps = {ts[dp][0], ts[dp][1], ts[dp][2], ts[dp][3]};
        *(bf16x4*)&xdT[off] = pd;
        *(bf16x4*)&xsT[off] = ps;
      }
    }
    __syncthreads();

    // --- P = mask(G * decay) -> LDS (wave-private rows wm..wm+15)
#pragma unroll
    for (int ct = 0; ct < 4; ct++) {
      int s = ct * 16 + r15;
      float as = acvA[hh * 64 + s];
#pragma unroll
      for (int i = 0; i < 4; i++) {
        int l = wm + quad * 4 + i;
        float pv = (s <= l) ? accg[ct][i] * __expf(acvA[hh * 64 + l] - as) : 0.f;
        P[l * 64 + (((s >> 3) ^ (l & 7)) << 3) + (s & 7)] = __float2bfloat16(pv);
      }
    }
    // --- Y_diag = P.xd (K=64) + xh*D
    f32x4 accy[4];
    for (int ct = 0; ct < 4; ct++) accy[ct] = zz;
#pragma unroll
    for (int ks = 0; ks < 2; ks++) {
      int arow = wm + r15;
      bf16x8 af = *(const bf16x8*)&P[arow * 64 + (((ks * 4 + quad) ^ (r15 & 7)) << 3)];
#pragma unroll
      for (int ct = 0; ct < 4; ct++) {
        int brow = ct * 16 + r15;
        bf16x8 bfr = *(const bf16x8*)&xdT[brow * 64 + (((ks * 4 + quad) ^ (r15 & 7)) << 3)];
        accy[ct] = __builtin_amdgcn_mfma_f32_16x16x32_bf16(af, bfr, accy[ct], 0, 0, 0);
      }
    }
    float Dh = Dp[h];
#pragma unroll
    for (int ct = 0; ct < 4; ct++) {
      int p = ct * 16 + r15;
#pragma unroll
      for (int i = 0; i < 4; i++) {
        int l = wm + quad * 4 + i;
        float xv = __bfloat162float(xh[(size_t)(base + l) * DIN + h * HD + p]);
        ypart[(size_t)(base + l) * DIN + h * HD + p] = __float2bfloat16(accy[ct][i] + xv * Dh);
      }
    }
    // --- S^T[p][n] = sum_l xs[l][p] * B[l][n]  (K=64, wave strip over p)
    f32x4 accs[8];
    for (int ct = 0; ct < 8; ct++) accs[ct] = zz;
#pragma unroll
    for (int ks = 0; ks < 2; ks++) {
      int arow = wm + r15;   // p row
      bf16x8 af = *(const bf16x8*)&xsT[arow * 64 + (((ks * 4 + quad) ^ (r15 & 7)) << 3)];
#pragma unroll
      for (int ct = 0; ct < 8; ct++) {
        int brow = ct * 16 + r15;   // n row
        bf16x8 bfr = *(const bf16x8*)&BT[brow * 64 + (((ks * 4 + quad) ^ (r15 & 7)) << 3)];
        accs[ct] = __builtin_amdgcn_mfma_f32_16x16x32_bf16(af, bfr, accs[ct], 0, 0, 0);
      }
    }
    size_t sbase = ((size_t)bc * NH + h) * (HD * DSTATE);
#pragma unroll
    for (int ct = 0; ct < 8; ct++) {
      int n = ct * 16 + r15;
#pragma unroll
      for (int i = 0; i < 4; i++) {
        int p = wm + quad * 4 + i;
        statesT[sbase + (size_t)p * DSTATE + n] = __float2bfloat16(accs[ct][i]);
      }
    }
    __syncthreads();   // before next head overwrites xdT/xsT
  }
}

// ---------------- K5: inter-chunk scan (in-place, layout [bc][h][p][n]) ----
__global__ __launch_bounds__(256) void k_scan(__hip_bfloat16* __restrict__ states,
    const float* __restrict__ echunk) {
  int idx = blockIdx.x * 256 + threadIdx.x;   // 524288
  int inner = idx & 8191;          // p*128+n
  int h = (idx >> 13) & 31;
  int b = idx >> 18;
  float run = 0.f;
  for (int c = 0; c < NCH; c++) {
    int bc = b * NCH + c;
    size_t off = ((size_t)bc * NH + h) * 8192 + inner;
    float tmp = __bfloat162float(states[off]);
    states[off] = __float2bfloat16(run);
    run = run * echunk[bc * NH + h] + tmp;
  }
}

// ---------------- K6: y += exp(acum) * (C . S_in^T), in-place bf16 ---------
__global__ __launch_bounds__(256) void k_ssd2(
    const __hip_bfloat16* __restrict__ statesT, const __hip_bfloat16* __restrict__ Cm,
    const float* __restrict__ acum, __hip_bfloat16* __restrict__ y) {
  __shared__ __attribute__((aligned(16))) __hip_bfloat16 Cb[64 * 128];  // [l][n] swz
  __shared__ __attribute__((aligned(16))) __hip_bfloat16 Sb[64 * 128];  // [p][n] swz
  __shared__ __attribute__((aligned(16))) __hip_bfloat16 Yt[64 * 64];   // [l][p]
  __shared__ float aout[64];
  int bc = blockIdx.x, h = blockIdx.y;
  int base = bc * CH;
  int tid = threadIdx.x, wid = tid >> 6, lane = tid & 63;
  int r15 = lane & 15, quad = lane >> 4;
  int wm = wid * 16;

  if (tid < 64) aout[tid] = __expf(acum[(base + tid) * NH + h]);
  size_t sbase = ((size_t)bc * NH + h) * (HD * DSTATE);
  {
    int srow = lane >> 4, g = lane & 15;
    for (int c = 0; c < 4; c++) {
      int R0 = wid * 16 + c * 4;
      int r = R0 + srow;
      int gs = g ^ (r & 7);
      gload_lds16(Cm + (size_t)(base + r) * DSTATE + gs * 8, &Cb[R0 * DSTATE]);
      gload_lds16(statesT + sbase + (size_t)r * DSTATE + gs * 8, &Sb[R0 * DSTATE]);
    }
    for (int c = 0; c < 2; c++) {
      int R0 = wid * 16 + c * 8;
      int r = R0 + (lane >> 3);
      gload_lds16(y + (size_t)(base + r) * DIN + h * HD + (lane & 7) * 8, &Yt[R0 * 64]);
    }
  }
  __syncthreads();

  f32x4 acc[4];
  f32x4 zz = {0.f, 0.f, 0.f, 0.f};
  for (int ct = 0; ct < 4; ct++) acc[ct] = zz;
#pragma unroll
  for (int ks = 0; ks < 4; ks++) {
    int arow = wm + r15;
    bf16x8 af = *(const bf16x8*)&Cb[arow * 128 + (((ks * 4 + quad) ^ (r15 & 7)) << 3)];
#pragma unroll
    for (int ct = 0; ct < 4; ct++) {
      int brow = ct * 16 + r15;
      bf16x8 bfr = *(const bf16x8*)&Sb[brow * 128 + (((ks * 4 + quad) ^ (r15 & 7)) << 3)];
      acc[ct] = __builtin_amdgcn_mfma_f32_16x16x32_bf16(af, bfr, acc[ct], 0, 0, 0);
    }
  }
#pragma unroll
  for (int ct = 0; ct < 4; ct++) {
    int p = ct * 16 + r15;
#pragma unroll
    for (int i = 0; i < 4; i++) {
      int l = wm + quad * 4 + i;
      float v = __bfloat162float(Yt[l * 64 + p]) + aout[l] * acc[ct][i];
      y[(size_t)(base + l) * DIN + h * HD + p] = __float2bfloat16(v);
    }
  }
}

extern "C" void kernel_launch(void* const* d_in, const int* in_sizes, int n_in,
                              void* d_out, int out_size, void* d_ws, size_t ws_size,
                              hipStream_t stream) {
  const float* x       = (const float*)d_in[0];
  const float* in_w    = (const float*)d_in[1];
  const float* conv_w  = (const float*)d_in[2];
  const float* conv_b  = (const float*)d_in[3];
  const float* dt_bias = (const float*)d_in[4];
  const float* A_log   = (const float*)d_in[5];
  const float* Dp      = (const float*)d_in[6];
  const float* out_w   = (const float*)d_in[7];
  float* out = (float*)d_out;

  char* cur = (char*)d_ws;
  auto alloc = [&](size_t bytes) {
    char* p = cur;
    cur += (bytes + 255) & ~(size_t)255;
    return p;
  };
  __hip_bfloat16* xbc   = (__hip_bfloat16*)alloc((size_t)T_TOK * CONVD * 2);
  float* dtb            = (float*)alloc((size_t)T_TOK * NH * 4);
  float* acum           = (float*)alloc((size_t)T_TOK * NH * 4);
  float* echunk         = (float*)alloc((size_t)NBC * NH * 4);
  __hip_bfloat16* xh    = (__hip_bfloat16*)alloc((size_t)T_TOK * DIN * 2);
  __hip_bfloat16* Bm    = (__hip_bfloat16*)alloc((size_t)T_TOK * DSTATE * 2);
  __hip_bfloat16* Cm    = (__hip_bfloat16*)alloc((size_t)T_TOK * DSTATE * 2);
  __hip_bfloat16* ybuf  = (__hip_bfloat16*)alloc((size_t)T_TOK * DIN * 2);
  __hip_bfloat16* states= (__hip_bfloat16*)alloc((size_t)NBC * NH * HD * DSTATE * 2);
  __hip_bfloat16* wib   = (__hip_bfloat16*)alloc((size_t)NPAD * DM * 2);
  __hip_bfloat16* wob   = (__hip_bfloat16*)alloc((size_t)DIN * DM * 2);
  __hip_bfloat16* xb    = states;   // alias: xb dead before k_ssd1 writes states

  k_pre    <<<dim3(9312), 256, 0, stream>>>(x, xb, in_w, wib, out_w, wob);
  k_gemm3<DM, true><<<dim3(NPAD / 128, T_TOK / 128), 256, 0, stream>>>(
      xb, wib, nullptr, xbc, dtb, dt_bias, 0);
  k_conv   <<<dim3(3, T_TOK), 256, 0, stream>>>(xbc, conv_w, conv_b, xh, Bm, Cm);
  k_ssd1   <<<dim3(NBC, 4),   256, 0, stream>>>(xh, Bm, Cm, dtb, A_log, Dp, ybuf, states, acum, echunk);
  k_scan   <<<dim3(2048),     256, 0, stream>>>(states, echunk);
  k_ssd2   <<<dim3(NBC, NH),  256, 0, stream>>>(states, Cm, acum, ybuf);
  k_gemm3<DIN, false><<<dim3(DM / 128, T_TOK / 128), 256, 0, stream>>>(
      ybuf, wob, out, nullptr, nullptr, nullptr, DM);
}

// Round 7
// 351.603 us; speedup vs baseline: 1.1051x; 1.0124x over previous
//
#include <hip/hip_runtime.h>
#include <hip/hip_bf16.h>
#include <math.h>
#include <stdint.h>

#define T_TOK 8192      // b*l
#define L_SEQ 4096
#define DM    1024
#define DIN   2048
#define DSTATE 128
#define NH    32
#define HD    64
#define CH    64        // chunk length
#define NCH   64        // chunks per batch
#define NBC   128       // B * NCH
#define CONVD 2304
#define NPROJ 2336      // columns of in_proj we actually need (z gate unused)
#define NPAD  2432      // NPROJ padded to multiple of 128
#define PROJ_OFF 2048
#define DPROJ 4384

typedef __bf16 bf16x8 __attribute__((ext_vector_type(8)));
typedef __bf16 bf16x4 __attribute__((ext_vector_type(4)));
typedef __bf16 bf16x2 __attribute__((ext_vector_type(2)));
typedef float f32x4 __attribute__((ext_vector_type(4)));

__device__ __forceinline__ void gload_lds16(const void* g, void* l) {
  __builtin_amdgcn_global_load_lds(
      (const __attribute__((address_space(1))) void*)(uintptr_t)g,
      (__attribute__((address_space(3))) void*)(uintptr_t)l, 16, 0, 0);
}

// ---------------- K0: fused preprocessing: cast x + transpose both weights --
__global__ __launch_bounds__(256) void k_pre(const float* __restrict__ x,
    __hip_bfloat16* __restrict__ xb, const float* __restrict__ in_w,
    __hip_bfloat16* __restrict__ wib, const float* __restrict__ out_w,
    __hip_bfloat16* __restrict__ wob) {
  __shared__ float s[64][65];
  int bid = blockIdx.x;
  if (bid < 8192) {                       // cast x -> bf16
    int i = (bid * 256 + threadIdx.x) * 4;
    float4 v = *(const float4*)(x + i);
    bf16x4 r;
    r[0] = (__bf16)v.x; r[1] = (__bf16)v.y; r[2] = (__bf16)v.z; r[3] = (__bf16)v.w;
    *(bf16x4*)(xb + i) = r;
    return;
  }
  const float* w; __hip_bfloat16* wt;
  int K, ldsrc, colOff, ncols, kx, ny;
  if (bid < 8800) {                       // in_proj weight transpose
    int b2 = bid - 8192; kx = b2 & 15; ny = b2 >> 4;
    w = in_w; wt = wib; K = DM; ldsrc = DPROJ; colOff = PROJ_OFF; ncols = NPROJ;
  } else {                                // out_proj weight transpose
    int b3 = bid - 8800; kx = b3 & 31; ny = b3 >> 5;
    w = out_w; wt = wob; K = DIN; ldsrc = DM; colOff = 0; ncols = DM;
  }
  int k0 = kx * 64, n0 = ny * 64;
  int c = threadIdx.x & 63, r0 = threadIdx.x >> 6;
  for (int i = 0; i < 16; i++) {
    int r = r0 + 4 * i;
    int ng = n0 + c;
    s[r][c] = (ng < ncols) ? w[(size_t)(k0 + r) * ldsrc + colOff + ng] : 0.f;
  }
  __syncthreads();
  for (int i = 0; i < 16; i++) {
    int a = r0 + 4 * i;
    wt[(size_t)(n0 + a) * K + k0 + c] = __float2bfloat16(s[c][a]);
  }
}

// ---------------- MFMA GEMM v3: 128x128 tile, operand-swapped epilogue ------
template <int KDIM, bool SPLIT>
__global__ __launch_bounds__(256) void k_gemm3(
    const __hip_bfloat16* __restrict__ A, const __hip_bfloat16* __restrict__ Bt,
    float* __restrict__ C, __hip_bfloat16* __restrict__ Cb16,
    float* __restrict__ dtb, const float* __restrict__ dt_bias, int NLD) {
  __shared__ __attribute__((aligned(16))) __hip_bfloat16 sA[128 * 64];
  __shared__ __attribute__((aligned(16))) __hip_bfloat16 sB[128 * 64];
  int tid = threadIdx.x;
  int wid = tid >> 6, lane = tid & 63;
  int t0 = blockIdx.y * 128, n0 = blockIdx.x * 128;
  int wm = (wid >> 1) * 64, wn = (wid & 1) * 64;
  int r15 = lane & 15, quad = lane >> 4;
  int srow = lane >> 3;
  int kcs = lane & 7;

  f32x4 acc[4][4];
  f32x4 zz = {0.f, 0.f, 0.f, 0.f};
  for (int ni = 0; ni < 4; ni++)
    for (int ti = 0; ti < 4; ti++) acc[ni][ti] = zz;

  const __hip_bfloat16* Abase = A + (size_t)t0 * KDIM;
  const __hip_bfloat16* Bbase = Bt + (size_t)n0 * KDIM;

  for (int k0 = 0; k0 < KDIM; k0 += 64) {
    for (int c = 0; c < 4; c++) {
      int R0 = (wid * 4 + c) * 8;
      int row = R0 + srow;
      int kcg = kcs ^ (row & 7);
      gload_lds16(Abase + (size_t)row * KDIM + k0 + kcg * 8, &sA[R0 * 64]);
      gload_lds16(Bbase + (size_t)row * KDIM + k0 + kcg * 8, &sB[R0 * 64]);
    }
    __syncthreads();
#pragma unroll
    for (int s = 0; s < 2; s++) {
      int sw = ((s << 2) | quad) ^ (r15 & 7);
      bf16x8 wf[4], xf[4];
#pragma unroll
      for (int ni = 0; ni < 4; ni++)
        wf[ni] = *reinterpret_cast<const bf16x8*>(&sB[(wn + ni * 16 + r15) * 64 + sw * 8]);
#pragma unroll
      for (int ti = 0; ti < 4; ti++)
        xf[ti] = *reinterpret_cast<const bf16x8*>(&sA[(wm + ti * 16 + r15) * 64 + sw * 8]);
#pragma unroll
      for (int ni = 0; ni < 4; ni++)
#pragma unroll
        for (int ti = 0; ti < 4; ti++)
          acc[ni][ti] = __builtin_amdgcn_mfma_f32_16x16x32_bf16(wf[ni], xf[ti], acc[ni][ti], 0, 0, 0);
    }
    __syncthreads();
  }

  // epilogue: D[n = quad*4+i][t = r15], vector stores over n
#pragma unroll
  for (int ni = 0; ni < 4; ni++) {
    int n = n0 + wn + ni * 16 + quad * 4;
#pragma unroll
    for (int ti = 0; ti < 4; ti++) {
      int t = t0 + wm + ti * 16 + r15;
      f32x4 v = acc[ni][ti];
      if (SPLIT) {
        if (n < CONVD) {
          bf16x4 r;
#pragma unroll
          for (int i = 0; i < 4; i++) r[i] = (__bf16)v[i];
          *(bf16x4*)(Cb16 + (size_t)t * CONVD + n) = r;
        } else if (n < NPROJ) {     // [CONVD, NPROJ) — 4-aligned boundary
#pragma unroll
          for (int i = 0; i < 4; i++) {
            int h = n + i - CONVD;
            float z = v[i] + dt_bias[h];
            float sp = (z > 20.f) ? z : log1pf(__expf(z));
            dtb[t * NH + h] = sp;
          }
        }
      } else {
        *(float4*)(C + (size_t)t * NLD + n) = *(float4*)&v;
      }
    }
  }
}

// ---------------- K2: depthwise causal conv(4) + bias + SiLU (4 ch/thread) --
__global__ __launch_bounds__(256) void k_conv(const __hip_bfloat16* __restrict__ xbc,
    const float* __restrict__ cw, const float* __restrict__ cb,
    __hip_bfloat16* __restrict__ xh, __hip_bfloat16* __restrict__ Bm,
    __hip_bfloat16* __restrict__ Cm) {
  int pi = blockIdx.x * 256 + threadIdx.x;
  if (pi >= CONVD / 4) return;
  int ch = pi * 4;
  int t = blockIdx.y;
  int l = t & (L_SEQ - 1);
  float4 cb4 = *(const float4*)(cb + ch);
  float acc[4] = {cb4.x, cb4.y, cb4.z, cb4.w};
#pragma unroll
  for (int j = 0; j < 4; j++) {
    int ls = l - 3 + j;
    if (ls >= 0) {
      bf16x4 v = *(const bf16x4*)(xbc + (size_t)(t - 3 + j) * CONVD + ch);
      float4 w4 = *(const float4*)(cw + j * CONVD + ch);
      acc[0] += (float)v[0] * w4.x;
      acc[1] += (float)v[1] * w4.y;
      acc[2] += (float)v[2] * w4.z;
      acc[3] += (float)v[3] * w4.w;
    }
  }
  bf16x4 r;
#pragma unroll
  for (int i = 0; i < 4; i++) {
    float sv = acc[i] / (1.f + __expf(-acc[i]));
    r[i] = (__bf16)sv;
  }
  if (ch < DIN)                 *(bf16x4*)(xh + (size_t)t * DIN + ch) = r;
  else if (ch < DIN + DSTATE)   *(bf16x4*)(Bm + (size_t)t * DSTATE + ch - DIN) = r;
  else                          *(bf16x4*)(Cm + (size_t)t * DSTATE + ch - DIN - DSTATE) = r;
}

// ---------------- K4: fused SSD per (chunk, 8 heads), acum folded in --------
// All transposed LDS arrays use stride-64 XOR-granule layout: element (row, k)
// stored at row*64 + ((k>>3)^(row&7))*8 + (k&7). Store/read swizzles cancel.
__global__ __launch_bounds__(256) void k_ssd1(
    const __hip_bfloat16* __restrict__ xh, const __hip_bfloat16* __restrict__ Bm,
    const __hip_bfloat16* __restrict__ Cm, const float* __restrict__ dtb,
    const float* __restrict__ A_log, const float* __restrict__ Dp,
    __hip_bfloat16* __restrict__ ypart, __hip_bfloat16* __restrict__ statesT,
    float* __restrict__ acum_out, float* __restrict__ echunk) {
  __shared__ __attribute__((aligned(16))) char smem[32768 + 8192 + 6144];
  __hip_bfloat16* Cb  = (__hip_bfloat16*)smem;            // 64x128 swz (phase 1)
  __hip_bfloat16* Bb  = Cb + 64 * 128;                    // 64x128 swz (phase 1)
  __hip_bfloat16* BT  = (__hip_bfloat16*)smem;            // 128x64 [n][l] (phase 2, alias)
  __hip_bfloat16* xdT = BT + 128 * 64;                    // 64x64 [p][l] x*dt
  __hip_bfloat16* xsT = xdT + 64 * 64;                    // 64x64 [p][l] x*dt*dec
  __hip_bfloat16* P   = (__hip_bfloat16*)(smem + 32768);  // 64x64 [l][s]
  float* acvA = (float*)(smem + 32768 + 8192);            // [8][64]
  float* dtsA = acvA + 512;
  float* decA = dtsA + 512;

  int bc = blockIdx.x, h0 = blockIdx.y * 8;
  int base = bc * CH;
  int tid = threadIdx.x, wid = tid >> 6, lane = tid & 63;
  int r15 = lane & 15, quad = lane >> 4;
  int wm = wid * 16;
  f32x4 zz = {0.f, 0.f, 0.f, 0.f};

  // stage Cb/Bb via async gload (row-granule XOR swizzle on global side)
  {
    int srow = lane >> 4, g = lane & 15;
    for (int c = 0; c < 4; c++) {
      int R0 = wid * 16 + c * 4;
      int r = R0 + srow;
      int gs = g ^ (r & 7);
      gload_lds16(Cm + (size_t)(base + r) * DSTATE + gs * 8, &Cb[R0 * DSTATE]);
      gload_lds16(Bm + (size_t)(base + r) * DSTATE + gs * 8, &Bb[R0 * DSTATE]);
    }
  }
  // preload dt (8 heads x 64 positions)
  for (int i = 0; i < 2; i++) {
    int idx = tid + 256 * i;
    int hh = idx >> 6, l = idx & 63;
    dtsA[hh * 64 + l] = dtb[(base + l) * NH + h0 + hh];
  }
  __syncthreads();
  // in-block cumsum of A*dt (one serial lane per head; 64 fp32 adds)
  if (tid < 8) {
    int h = h0 + tid;
    float a = -__expf(A_log[h]);
    float s = 0.f;
    for (int l = 0; l < CH; l++) {
      s += a * dtsA[tid * 64 + l];
      acvA[tid * 64 + l] = s;
    }
    echunk[bc * NH + h] = __expf(s);
  }
  __syncthreads();
  // dec + persist acum for k_ssd2
  for (int i = 0; i < 2; i++) {
    int idx = tid + 256 * i;
    int hh = idx >> 6, l = idx & 63;
    float a = acvA[hh * 64 + l];
    decA[hh * 64 + l] = __expf(acvA[hh * 64 + 63] - a);
    acum_out[(base + l) * NH + h0 + hh] = a;
  }

  // --- G = C.B^T once: wave strip rows wm..wm+15 x all 64 s (K=128)
  f32x4 accg[4];
  for (int ct = 0; ct < 4; ct++) accg[ct] = zz;
#pragma unroll
  for (int ks = 0; ks < 4; ks++) {
    int arow = wm + r15;
    bf16x8 af = *(const bf16x8*)&Cb[arow * 128 + (((ks * 4 + quad) ^ (r15 & 7)) << 3)];
#pragma unroll
    for (int ct = 0; ct < 4; ct++) {
      int brow = ct * 16 + r15;
      bf16x8 bfr = *(const bf16x8*)&Bb[brow * 128 + (((ks * 4 + quad) ^ (r15 & 7)) << 3)];
      accg[ct] = __builtin_amdgcn_mfma_f32_16x16x32_bf16(af, bfr, accg[ct], 0, 0, 0);
    }
  }
  __syncthreads();   // Cb/Bb dead; region reused below

  int l0 = (tid & 15) * 4;     // 4 consecutive l (same granule: l0%8 in {0,4})
  int q0 = tid >> 4;           // 0..15
  int go = l0 & 7;             // offset within granule
  int gl = l0 >> 3;            // true granule of l0

  for (int hh = 0; hh < 8; hh++) {
    int h = h0 + hh;
    if (hh == 0) {
      // build BT[n][l] once (head-independent, decay folded into xs)
      int n0 = q0 * 8;
      __bf16 tmp[8][4];
#pragma unroll
      for (int dl = 0; dl < 4; dl++) {
        bf16x8 bv = *(const bf16x8*)(Bm + (size_t)(base + l0 + dl) * DSTATE + n0);
#pragma unroll
        for (int dn = 0; dn < 8; dn++) tmp[dn][dl] = bv[dn];
      }
#pragma unroll
      for (int dn = 0; dn < 8; dn++) {
        int n = n0 + dn;
        bf16x4 pk = {tmp[dn][0], tmp[dn][1], tmp[dn][2], tmp[dn][3]};
        *(bf16x4*)&BT[n * 64 + ((gl ^ (n & 7)) << 3) + go] = pk;
      }
    }
    // build xdT (x*dt) and xsT (x*dt*dec) for this head: 4l x 4p per thread
    {
      int p0 = q0 * 4;
      __bf16 td[4][4], ts[4][4];
#pragma unroll
      for (int dl = 0; dl < 4; dl++) {
        int l = l0 + dl;
        bf16x4 xv = *(const bf16x4*)(xh + (size_t)(base + l) * DIN + h * HD + p0);
        float dt = dtsA[hh * 64 + l];
        float ds = dt * decA[hh * 64 + l];
#pragma unroll
        for (int dp = 0; dp < 4; dp++) {
          float xf = (float)xv[dp];
          td[dp][dl] = (__bf16)(xf * dt);
          ts[dp][dl] = (__bf16)(xf * ds);
        }
      }
#pragma unroll
      for (int dp = 0; dp < 4; dp++) {
        int p = p0 + dp;
        int off = p * 64 + ((gl ^ (p & 7)) << 3) + go;
        bf16x4 pd = {td[dp][0], td[dp][1], td[dp][2], td[dp][3]};
        bf16x4 ps = {ts[dp][0], ts[dp][1], ts[dp][2], ts[dp][3]};
        *(bf16x4*)&xdT[off] = pd;
        *(bf16x4*)&xsT[off] = ps;
      }
    }
    __syncthreads();

    // --- P = mask(G * decay) -> LDS (wave-private rows wm..wm+15)
#pragma unroll
    for (int ct = 0; ct < 4; ct++) {
      int s = ct * 16 + r15;
      float as = acvA[hh * 64 + s];
#pragma unroll
      for (int i = 0; i < 4; i++) {
        int l = wm + quad * 4 + i;
        float pv = (s <= l) ? accg[ct][i] * __expf(acvA[hh * 64 + l] - as) : 0.f;
        P[l * 64 + (((s >> 3) ^ (l & 7)) << 3) + (s & 7)] = __float2bfloat16(pv);
      }
    }
    // --- Y_diag = P.xd (K=64) + xh*D
    f32x4 accy[4];
    for (int ct = 0; ct < 4; ct++) accy[ct] = zz;
#pragma unroll
    for (int ks = 0; ks < 2; ks++) {
      int arow = wm + r15;
      bf16x8 af = *(const bf16x8*)&P[arow * 64 + (((ks * 4 + quad) ^ (r15 & 7)) << 3)];
#pragma unroll
      for (int ct = 0; ct < 4; ct++) {
        int brow = ct * 16 + r15;
        bf16x8 bfr = *(const bf16x8*)&xdT[brow * 64 + (((ks * 4 + quad) ^ (r15 & 7)) << 3)];
        accy[ct] = __builtin_amdgcn_mfma_f32_16x16x32_bf16(af, bfr, accy[ct], 0, 0, 0);
      }
    }
    float Dh = Dp[h];
#pragma unroll
    for (int ct = 0; ct < 4; ct++) {
      int p = ct * 16 + r15;
#pragma unroll
      for (int i = 0; i < 4; i++) {
        int l = wm + quad * 4 + i;
        float xv = __bfloat162float(xh[(size_t)(base + l) * DIN + h * HD + p]);
        ypart[(size_t)(base + l) * DIN + h * HD + p] = __float2bfloat16(accy[ct][i] + xv * Dh);
      }
    }
    // --- S^T[p][n] = sum_l xs[l][p] * B[l][n]  (K=64, wave strip over p)
    f32x4 accs[8];
    for (int ct = 0; ct < 8; ct++) accs[ct] = zz;
#pragma unroll
    for (int ks = 0; ks < 2; ks++) {
      int arow = wm + r15;   // p row
      bf16x8 af = *(const bf16x8*)&xsT[arow * 64 + (((ks * 4 + quad) ^ (r15 & 7)) << 3)];
#pragma unroll
      for (int ct = 0; ct < 8; ct++) {
        int brow = ct * 16 + r15;   // n row
        bf16x8 bfr = *(const bf16x8*)&BT[brow * 64 + (((ks * 4 + quad) ^ (r15 & 7)) << 3)];
        accs[ct] = __builtin_amdgcn_mfma_f32_16x16x32_bf16(af, bfr, accs[ct], 0, 0, 0);
      }
    }
    size_t sbase = ((size_t)bc * NH + h) * (HD * DSTATE);
#pragma unroll
    for (int ct = 0; ct < 8; ct++) {
      int n = ct * 16 + r15;
#pragma unroll
      for (int i = 0; i < 4; i++) {
        int p = wm + quad * 4 + i;
        statesT[sbase + (size_t)p * DSTATE + n] = __float2bfloat16(accs[ct][i]);
      }
    }
    __syncthreads();   // before next head overwrites xdT/xsT
  }
}

// ---------------- K5: inter-chunk scan (in-place, 2 elems/thread) ----------
__global__ __launch_bounds__(256) void k_scan(__hip_bfloat16* __restrict__ states,
    const float* __restrict__ echunk) {
  int idx = blockIdx.x * 256 + threadIdx.x;   // 262144
  int inner = (idx & 4095) * 2;    // p*128+n, pair-aligned
  int h = (idx >> 12) & 31;
  int b = idx >> 17;
  float run0 = 0.f, run1 = 0.f;
  for (int c = 0; c < NCH; c++) {
    int bc = b * NCH + c;
    size_t off = ((size_t)bc * NH + h) * 8192 + inner;
    bf16x2 v = *(bf16x2*)(states + off);
    bf16x2 w = {(__bf16)run0, (__bf16)run1};
    *(bf16x2*)(states + off) = w;
    float e = echunk[bc * NH + h];
    run0 = run0 * e + (float)v[0];
    run1 = run1 * e + (float)v[1];
  }
}

// ---------------- K6: y += exp(acum)*(C.S_in^T), 4 heads/block, C reused ---
__global__ __launch_bounds__(256) void k_ssd2(
    const __hip_bfloat16* __restrict__ statesT, const __hip_bfloat16* __restrict__ Cm,
    const float* __restrict__ acum, __hip_bfloat16* __restrict__ y) {
  __shared__ __attribute__((aligned(16))) __hip_bfloat16 Cb[64 * 128];  // [l][n] swz
  __shared__ __attribute__((aligned(16))) __hip_bfloat16 Sb[64 * 128];  // [p][n] swz
  __shared__ __attribute__((aligned(16))) __hip_bfloat16 Yt[64 * 64];   // [l][p]
  __shared__ float aout[4 * 64];
  int bc = blockIdx.x, h0 = blockIdx.y * 4;
  int base = bc * CH;
  int tid = threadIdx.x, wid = tid >> 6, lane = tid & 63;
  int r15 = lane & 15, quad = lane >> 4;
  int wm = wid * 16;
  int srow = lane >> 4, g = lane & 15;

  aout[tid] = __expf(acum[(base + (tid & 63)) * NH + h0 + (tid >> 6)]);
  // stage Cb once (reused for all 4 heads)
  for (int c = 0; c < 4; c++) {
    int R0 = wid * 16 + c * 4;
    int r = R0 + srow;
    int gs = g ^ (r & 7);
    gload_lds16(Cm + (size_t)(base + r) * DSTATE + gs * 8, &Cb[R0 * DSTATE]);
  }

  for (int hh = 0; hh < 4; hh++) {
    int h = h0 + hh;
    size_t sbase = ((size_t)bc * NH + h) * (HD * DSTATE);
    // stage Sb + Yt for this head
    for (int c = 0; c < 4; c++) {
      int R0 = wid * 16 + c * 4;
      int r = R0 + srow;
      int gs = g ^ (r & 7);
      gload_lds16(statesT + sbase + (size_t)r * DSTATE + gs * 8, &Sb[R0 * DSTATE]);
    }
    for (int c = 0; c < 2; c++) {
      int R0 = wid * 16 + c * 8;
      int r = R0 + (lane >> 3);
      gload_lds16(y + (size_t)(base + r) * DIN + h * HD + (lane & 7) * 8, &Yt[R0 * 64]);
    }
    __syncthreads();

    f32x4 acc[4];
    f32x4 zz = {0.f, 0.f, 0.f, 0.f};
    for (int ct = 0; ct < 4; ct++) acc[ct] = zz;
#pragma unroll
    for (int ks = 0; ks < 4; ks++) {
      int arow = wm + r15;
      bf16x8 af = *(const bf16x8*)&Cb[arow * 128 + (((ks * 4 + quad) ^ (r15 & 7)) << 3)];
#pragma unroll
      for (int ct = 0; ct < 4; ct++) {
        int brow = ct * 16 + r15;
        bf16x8 bfr = *(const bf16x8*)&Sb[brow * 128 + (((ks * 4 + quad) ^ (r15 & 7)) << 3)];
        acc[ct] = __builtin_amdgcn_mfma_f32_16x16x32_bf16(af, bfr, acc[ct], 0, 0, 0);
      }
    }
#pragma unroll
    for (int ct = 0; ct < 4; ct++) {
      int p = ct * 16 + r15;
#pragma unroll
      for (int i = 0; i < 4; i++) {
        int l = wm + quad * 4 + i;
        float v = __bfloat162float(Yt[l * 64 + p]) + aout[hh * 64 + l] * acc[ct][i];
        y[(size_t)(base + l) * DIN + h * HD + p] = __float2bfloat16(v);
      }
    }
    __syncthreads();   // before next head's staging overwrites Sb/Yt
  }
}

extern "C" void kernel_launch(void* const* d_in, const int* in_sizes, int n_in,
                              void* d_out, int out_size, void* d_ws, size_t ws_size,
                              hipStream_t stream) {
  const float* x       = (const float*)d_in[0];
  const float* in_w    = (const float*)d_in[1];
  const float* conv_w  = (const float*)d_in[2];
  const float* conv_b  = (const float*)d_in[3];
  const float* dt_bias = (const float*)d_in[4];
  const float* A_log   = (const float*)d_in[5];
  const float* Dp      = (const float*)d_in[6];
  const float* out_w   = (const float*)d_in[7];
  float* out = (float*)d_out;

  char* cur = (char*)d_ws;
  auto alloc = [&](size_t bytes) {
    char* p = cur;
    cur += (bytes + 255) & ~(size_t)255;
    return p;
  };
  __hip_bfloat16* xbc   = (__hip_bfloat16*)alloc((size_t)T_TOK * CONVD * 2);
  float* dtb            = (float*)alloc((size_t)T_TOK * NH * 4);
  float* acum           = (float*)alloc((size_t)T_TOK * NH * 4);
  float* echunk         = (float*)alloc((size_t)NBC * NH * 4);
  __hip_bfloat16* xh    = (__hip_bfloat16*)alloc((size_t)T_TOK * DIN * 2);
  __hip_bfloat16* Bm    = (__hip_bfloat16*)alloc((size_t)T_TOK * DSTATE * 2);
  __hip_bfloat16* Cm    = (__hip_bfloat16*)alloc((size_t)T_TOK * DSTATE * 2);
  __hip_bfloat16* ybuf  = (__hip_bfloat16*)alloc((size_t)T_TOK * DIN * 2);
  __hip_bfloat16* states= (__hip_bfloat16*)alloc((size_t)NBC * NH * HD * DSTATE * 2);
  __hip_bfloat16* wib   = (__hip_bfloat16*)alloc((size_t)NPAD * DM * 2);
  __hip_bfloat16* wob   = (__hip_bfloat16*)alloc((size_t)DIN * DM * 2);
  __hip_bfloat16* xb    = states;   // alias: xb dead before k_ssd1 writes states

  k_pre    <<<dim3(9312), 256, 0, stream>>>(x, xb, in_w, wib, out_w, wob);
  k_gemm3<DM, true><<<dim3(NPAD / 128, T_TOK / 128), 256, 0, stream>>>(
      xb, wib, nullptr, xbc, dtb, dt_bias, 0);
  k_conv   <<<dim3(3, T_TOK), 256, 0, stream>>>(xbc, conv_w, conv_b, xh, Bm, Cm);
  k_ssd1   <<<dim3(NBC, 4),   256, 0, stream>>>(xh, Bm, Cm, dtb, A_log, Dp, ybuf, states, acum, echunk);
  k_scan   <<<dim3(1024),     256, 0, stream>>>(states, echunk);
  k_ssd2   <<<dim3(NBC, 8),   256, 0, stream>>>(states, Cm, acum, ybuf);
  k_gemm3<DIN, false><<<dim3(DM / 128, T_TOK / 128), 256, 0, stream>>>(
      ybuf, wob, out, nullptr, nullptr, nullptr, DM);
}